// Round 4
// baseline (924.044 us; speedup 1.0000x reference)
//
#include <hip/hip_runtime.h>
#include <hip/hip_bf16.h>

#define F_IN 128
#define HID  64
#define NCLS 19
#define BW   128          // nodes per bucket window (dst >> 7)

// -------- adaptive loads: flags[0]=1 -> floats are fp32 (else bf16)
//          flags[1]=1 -> indices are int64 (else int32)
__device__ __forceinline__ float ldf(const void* p, long i, int fp32) {
    if (fp32) return ((const float*)p)[i];
    return __bfloat162float(((const __hip_bfloat16*)p)[i]);
}
__device__ __forceinline__ int ldi(const void* p, long i, int i64) {
    if (i64) return (int)((const long long*)p)[i];
    return ((const int*)p)[i];
}
__device__ __forceinline__ unsigned short f2bf(float f) {
    __hip_bfloat16 h = __float2bfloat16(f);   // RNE
    unsigned short r;
    __builtin_memcpy(&r, &h, 2);
    return r;
}
__device__ __forceinline__ float bflo(unsigned u) { return __uint_as_float(u << 16); }
__device__ __forceinline__ float bfhi(unsigned u) { return __uint_as_float(u & 0xffff0000u); }

// ---------------- dtype sniffer ----------------
__global__ void k_detect(const void* x, const void* ei, int* flags) {
    if (threadIdx.x != 0) return;
    const unsigned* xw = (const unsigned*)x;
    int bf16 = 1;
    for (int i = 0; i < 16; ++i) {
        unsigned w = xw[i];
        int elo = (w >> 7) & 0xFF;
        int ehi = (w >> 23) & 0xFF;
        if (elo < 100 || elo > 140 || ehi < 100 || ehi > 140) bf16 = 0;
    }
    const unsigned* iw = (const unsigned*)ei;
    int i64 = 1; unsigned anyev = 0;
    for (int k = 0; k < 8; ++k) {
        if (iw[2 * k + 1] != 0) i64 = 0;
        anyev |= iw[2 * k];
    }
    if (anyev == 0) i64 = 0;
    flags[0] = bf16 ? 0 : 1;
    flags[1] = i64;
}

// ---------------- degree histogram (in-degree on dst) ----------------
__global__ void k_deg(const void* __restrict__ ei, int E, int* __restrict__ deg,
                      const int* __restrict__ flags) {
    int i64 = flags[1];
    int e = blockIdx.x * 256 + threadIdx.x;
    if (e < E) atomicAdd(&deg[ldi(ei, (long)E + e, i64)], 1);
}

// ---------------- scan stage 1: per-bucket degree sums (coalesced) ----------------
__global__ __launch_bounds__(BW) void k_scan1(const int* __restrict__ deg, int N,
                                              int* __restrict__ bsum) {
    __shared__ int s[BW];
    int b = blockIdx.x, t = threadIdx.x;
    int n = b * BW + t;
    s[t] = (n < N) ? deg[n] : 0;
    __syncthreads();
    for (int off = BW / 2; off >= 1; off >>= 1) {
        if (t < off) s[t] += s[t + off];
        __syncthreads();
    }
    if (t == 0) bsum[b] = s[0];
}

// ---------------- scan stage 2: exclusive scan of bucket sums (1 block) ----------------
__global__ __launch_bounds__(1024) void k_scan2(const int* __restrict__ bsum, int NB,
                                                int* __restrict__ bbase, int E) {
    __shared__ int s[1024];
    int t = threadIdx.x;
    int v = (t < NB) ? bsum[t] : 0;
    s[t] = v;
    __syncthreads();
    for (int off = 1; off < 1024; off <<= 1) {
        int x = (t >= off) ? s[t - off] : 0;
        __syncthreads();
        s[t] += x;
        __syncthreads();
    }
    if (t < NB) bbase[t] = s[t] - v;   // exclusive
    if (t == 0) bbase[NB] = E;
}

// ---------------- scan stage 3: per-node cursor (row start), dinv, bucket cursor init ----------------
__global__ __launch_bounds__(BW) void k_scan3(const int* __restrict__ deg, int N,
                                              const int* __restrict__ bbase,
                                              int* __restrict__ cursor,
                                              float* __restrict__ dinv,
                                              int* __restrict__ bcur) {
    __shared__ int s[BW];
    int b = blockIdx.x, t = threadIdx.x;
    int n = b * BW + t;
    int v = (n < N) ? deg[n] : 0;
    s[t] = v;
    __syncthreads();
    for (int off = 1; off < BW; off <<= 1) {
        int x = (t >= off) ? s[t - off] : 0;
        __syncthreads();
        s[t] += x;
        __syncthreads();
    }
    if (n < N) {
        cursor[n] = bbase[b] + s[t] - v;        // exclusive row start
        dinv[n] = rsqrtf((float)(v + 1));       // +1 self-loop
    }
    if (t == 0) bcur[b] = bbase[b];
}

// ---------------- fill pass 1: scatter edges into coarse buckets (sequential per-bucket writes) ----------------
__global__ void k_fill1(const void* __restrict__ ei, int E,
                        int* bcur, int* __restrict__ bkt,
                        const int* __restrict__ flags) {
    int i64 = flags[1];
    int e = blockIdx.x * 256 + threadIdx.x;
    if (e < E) {
        int s = ldi(ei, e, i64);
        int d = ldi(ei, (long)E + e, i64);
        int pos = atomicAdd(&bcur[d >> 7], 1);
        bkt[pos] = (s << 7) | (d & (BW - 1));
    }
}

// ---------------- fill pass 2: per-bucket LDS-cursor scatter into final CSR (local writes) ----------------
__global__ __launch_bounds__(256) void k_fill2(const int* __restrict__ bkt,
                                               const int* __restrict__ bbase,
                                               const int* __restrict__ cursor,
                                               int N, int* __restrict__ csr) {
    __shared__ int lcur[BW];
    int b = blockIdx.x, t = threadIdx.x;
    if (t < BW) {
        int n = b * BW + t;
        lcur[t] = (n < N) ? cursor[n] : 0;
    }
    __syncthreads();
    int base = bbase[b], end = bbase[b + 1];
    for (int e = base + t; e < end; e += 256) {
        int w = bkt[e];
        int pos = atomicAdd(&lcur[w & (BW - 1)], 1);
        csr[pos] = w >> 7;
    }
}

// ---------------- GEMM1: t[i,:] = bf16(dinv[i] * (x[i,:] @ W1)) ----------------
__global__ __launch_bounds__(256) void k_gemm1(const void* __restrict__ x,
                                               const void* __restrict__ W,
                                               const float* __restrict__ dinv,
                                               unsigned short* __restrict__ t, int N,
                                               const int* __restrict__ flags) {
    __shared__ __align__(16) float wl[F_IN * HID];   // 32 KB
    __shared__ __align__(16) float xl[32 * F_IN];    // 16 KB
    int fp32 = flags[0];
    int tid = threadIdx.x;
    for (int i = tid; i < F_IN * HID; i += 256) wl[i] = ldf(W, i, fp32);
    int row0 = blockIdx.x * 32;
    for (int i = tid; i < 32 * F_IN; i += 256) {
        int r = row0 + (i >> 7);
        xl[i] = (r < N) ? ldf(x, (long)r * F_IN + (i & 127), fp32) : 0.f;
    }
    __syncthreads();
    int w = tid >> 6, j = tid & 63;
    float acc[8];
#pragma unroll
    for (int r = 0; r < 8; ++r) acc[r] = 0.f;
    const float4* x4 = (const float4*)(xl + w * 8 * F_IN);
#pragma unroll 2
    for (int k = 0; k < F_IN; k += 4) {
        float wv0 = wl[k * HID + j];
        float wv1 = wl[(k + 1) * HID + j];
        float wv2 = wl[(k + 2) * HID + j];
        float wv3 = wl[(k + 3) * HID + j];
#pragma unroll
        for (int r = 0; r < 8; ++r) {
            float4 xv = x4[(r * F_IN + k) >> 2];
            acc[r] += xv.x * wv0;
            acc[r] += xv.y * wv1;
            acc[r] += xv.z * wv2;
            acc[r] += xv.w * wv3;
        }
    }
#pragma unroll
    for (int r = 0; r < 8; ++r) {
        int row = row0 + w * 8 + r;
        if (row < N) t[(size_t)row * HID + j] = f2bf(dinv[row] * acc[r]);
    }
}

// ---------------- GEMM2: t[i,:] = bf16(dinv[i] * (h[i,:] @ W2)), h bf16 ----------------
__global__ __launch_bounds__(256) void k_gemm2(const unsigned short* __restrict__ h,
                                               const void* __restrict__ W,
                                               const float* __restrict__ dinv,
                                               unsigned short* __restrict__ t, int N,
                                               const int* __restrict__ flags) {
    __shared__ __align__(16) float wl[HID * HID];   // 16 KB
    __shared__ __align__(16) float xl[32 * HID];    // 8 KB
    int fp32 = flags[0];
    int tid = threadIdx.x;
    for (int i = tid; i < HID * HID; i += 256) wl[i] = ldf(W, i, fp32);
    int row0 = blockIdx.x * 32;
    for (int i = tid; i < 32 * HID; i += 256) {
        int r = row0 + (i >> 6);
        xl[i] = (r < N) ? bflo((unsigned)h[(size_t)r * HID + (i & 63)]) : 0.f;
    }
    __syncthreads();
    int w = tid >> 6, j = tid & 63;
    float acc[8];
#pragma unroll
    for (int r = 0; r < 8; ++r) acc[r] = 0.f;
    const float4* x4 = (const float4*)(xl + w * 8 * HID);
#pragma unroll 2
    for (int k = 0; k < HID; k += 4) {
        float wv0 = wl[k * HID + j];
        float wv1 = wl[(k + 1) * HID + j];
        float wv2 = wl[(k + 2) * HID + j];
        float wv3 = wl[(k + 3) * HID + j];
#pragma unroll
        for (int r = 0; r < 8; ++r) {
            float4 xv = x4[(r * HID + k) >> 2];
            acc[r] += xv.x * wv0;
            acc[r] += xv.y * wv1;
            acc[r] += xv.z * wv2;
            acc[r] += xv.w * wv3;
        }
    }
#pragma unroll
    for (int r = 0; r < 8; ++r) {
        int row = row0 + w * 8 + r;
        if (row < N) t[(size_t)row * HID + j] = f2bf(dinv[row] * acc[r]);
    }
}

// ---------------- aggregation: one wave per node, 4 row-gathers in flight ----------------
// out[d,:] = bf16( relu?( dinv[d]*(sum_{s in in(d)} t[s,:] + t[d,:]) + b ) )
template <bool RELU>
__global__ __launch_bounds__(256) void k_agg(const unsigned short* __restrict__ t,
                                             const int* __restrict__ csr,
                                             const int* __restrict__ cursor,
                                             const int* __restrict__ deg,
                                             const float* __restrict__ dinv,
                                             const void* __restrict__ bias,
                                             unsigned short* __restrict__ out,
                                             int N, const int* __restrict__ flags) {
    int node = blockIdx.x * 4 + (threadIdx.x >> 6);
    if (node >= N) return;
    int lane = threadIdx.x & 63;
    int g = lane >> 4;          // neighbor group 0..3
    int l4 = (lane & 15) * 4;   // this lane's 4 features
    int beg = cursor[node];
    int end = beg + deg[node];
    float a0 = 0.f, a1 = 0.f, a2 = 0.f, a3 = 0.f;
    for (int e = beg; e < end; e += 16) {
        int i0 = e + g, i1 = e + 4 + g, i2 = e + 8 + g, i3 = e + 12 + g;
        int s0 = csr[i0 < end ? i0 : end - 1];
        int s1 = csr[i1 < end ? i1 : end - 1];
        int s2 = csr[i2 < end ? i2 : end - 1];
        int s3 = csr[i3 < end ? i3 : end - 1];
        uint2 v0 = *(const uint2*)(t + s0 * HID + l4);
        uint2 v1 = *(const uint2*)(t + s1 * HID + l4);
        uint2 v2 = *(const uint2*)(t + s2 * HID + l4);
        uint2 v3 = *(const uint2*)(t + s3 * HID + l4);
        if (i0 < end) { a0 += bflo(v0.x); a1 += bfhi(v0.x); a2 += bflo(v0.y); a3 += bfhi(v0.y); }
        if (i1 < end) { a0 += bflo(v1.x); a1 += bfhi(v1.x); a2 += bflo(v1.y); a3 += bfhi(v1.y); }
        if (i2 < end) { a0 += bflo(v2.x); a1 += bfhi(v2.x); a2 += bflo(v2.y); a3 += bfhi(v2.y); }
        if (i3 < end) { a0 += bflo(v3.x); a1 += bfhi(v3.x); a2 += bflo(v3.y); a3 += bfhi(v3.y); }
    }
    // combine the 4 neighbor groups
    a0 += __shfl_xor(a0, 16); a0 += __shfl_xor(a0, 32);
    a1 += __shfl_xor(a1, 16); a1 += __shfl_xor(a1, 32);
    a2 += __shfl_xor(a2, 16); a2 += __shfl_xor(a2, 32);
    a3 += __shfl_xor(a3, 16); a3 += __shfl_xor(a3, 32);
    // self-loop
    uint2 sv = *(const uint2*)(t + node * HID + l4);
    a0 += bflo(sv.x); a1 += bfhi(sv.x);
    a2 += bflo(sv.y); a3 += bfhi(sv.y);
    int fp32 = flags[0];
    float di = dinv[node];
    float v0 = di * a0 + ldf(bias, l4 + 0, fp32);
    float v1 = di * a1 + ldf(bias, l4 + 1, fp32);
    float v2 = di * a2 + ldf(bias, l4 + 2, fp32);
    float v3 = di * a3 + ldf(bias, l4 + 3, fp32);
    if (RELU) {
        v0 = fmaxf(v0, 0.f); v1 = fmaxf(v1, 0.f);
        v2 = fmaxf(v2, 0.f); v3 = fmaxf(v3, 0.f);
    }
    if (g == 0) {
        uint2 pk;
        pk.x = (unsigned)f2bf(v0) | ((unsigned)f2bf(v1) << 16);
        pk.y = (unsigned)f2bf(v2) | ((unsigned)f2bf(v3) << 16);
        *(uint2*)(out + node * HID + l4) = pk;
    }
}

// ---------------- mean pool: batch sorted -> per-graph segment mean, atomic-free ----------------
__global__ __launch_bounds__(64) void k_pool(const unsigned short* __restrict__ h2,
                                             const void* __restrict__ batch, int N,
                                             float* __restrict__ pooled,
                                             const int* __restrict__ flags) {
    int g = blockIdx.x;
    int i64 = flags[1];
    int lo = 0, hi = N;
    while (lo < hi) { int mid = (lo + hi) >> 1; if (ldi(batch, mid, i64) < g) lo = mid + 1; else hi = mid; }
    int start = lo;
    hi = N;
    while (lo < hi) { int mid = (lo + hi) >> 1; if (ldi(batch, mid, i64) < g + 1) lo = mid + 1; else hi = mid; }
    int endg = lo;
    int lane = threadIdx.x;
    int half = lane >> 5;
    int l = lane & 31;
    float s0 = 0.f, s1 = 0.f;
    for (int r = start; r < endg; r += 4) {
        int r0 = r + half;
        int r1 = r + 2 + half;
        unsigned u0 = (r0 < endg) ? *(const unsigned*)(h2 + (size_t)r0 * HID + 2 * l) : 0u;
        unsigned u1 = (r1 < endg) ? *(const unsigned*)(h2 + (size_t)r1 * HID + 2 * l) : 0u;
        s0 += bflo(u0) + bflo(u1);
        s1 += bfhi(u0) + bfhi(u1);
    }
    s0 += __shfl_xor(s0, 32);
    s1 += __shfl_xor(s1, 32);
    if (lane < 32) {
        float inv = 1.f / fmaxf((float)(endg - start), 1.f);
        *(float2*)(pooled + (size_t)g * HID + 2 * l) = make_float2(s0 * inv, s1 * inv);
    }
}

// ---------------- head: out[g,:] = pooled[g,:] @ W_out + b_out ----------------
__global__ __launch_bounds__(64) void k_out(const float* __restrict__ pooled,
                                            const void* __restrict__ Wout,
                                            const void* __restrict__ bout,
                                            void* __restrict__ out, int G,
                                            const int* __restrict__ flags) {
    __shared__ float pr[HID];
    int fp32 = flags[0];
    int g = blockIdx.x;
    int tid = threadIdx.x;
    pr[tid] = pooled[(size_t)g * HID + tid];
    __syncthreads();
    if (tid < NCLS) {
        float acc = ldf(bout, tid, fp32);
#pragma unroll 4
        for (int k = 0; k < HID; ++k)
            acc += pr[k] * ldf(Wout, k * NCLS + tid, fp32);
        if (fp32) ((float*)out)[g * NCLS + tid] = acc;
        else ((__hip_bfloat16*)out)[g * NCLS + tid] = __float2bfloat16(acc);
    }
}

extern "C" void kernel_launch(void* const* d_in, const int* in_sizes, int n_in,
                              void* d_out, int out_size, void* d_ws, size_t ws_size,
                              hipStream_t stream) {
    const void* x    = d_in[0];
    const void* ei   = d_in[1];
    const void* bat  = d_in[2];
    const void* W1   = d_in[3];
    const void* b1   = d_in[4];
    const void* W2   = d_in[5];
    const void* b2   = d_in[6];
    const void* Wout = d_in[7];
    const void* bout = d_in[8];

    const int N = in_sizes[0] / F_IN;
    const int E = in_sizes[1] / 2;
    const int G = out_size / NCLS;
    const int NB = (N + BW - 1) / BW;

    char* ws = (char*)d_ws;
    size_t off = 0;
    auto carve = [&](size_t bytes) -> void* {
        void* p = ws + off;
        off = (off + bytes + 255) & ~(size_t)255;
        return p;
    };
    int*            flags  = (int*)carve(64);
    int*            deg    = (int*)carve((size_t)N * 4);
    int*            cursor = (int*)carve((size_t)N * 4);
    float*          dinv   = (float*)carve((size_t)N * 4);
    int*            bsum   = (int*)carve((size_t)NB * 4);
    int*            bbase  = (int*)carve((size_t)(NB + 1) * 4);
    int*            bcur   = (int*)carve((size_t)NB * 4);
    int*            csr    = (int*)carve((size_t)E * 4);
    int*            bkt    = (int*)carve((size_t)E * 4);
    unsigned short* t      = (unsigned short*)carve((size_t)N * HID * 2);
    unsigned short* h      = (unsigned short*)carve((size_t)N * HID * 2);
    float*          pooled = (float*)carve((size_t)G * HID * 4);
    (void)ws_size; (void)n_in;

    hipMemsetAsync(deg, 0, (size_t)N * 4, stream);

    k_detect<<<1, 64, 0, stream>>>(x, ei, flags);

    int eb = (E + 255) / 256;
    k_deg<<<eb, 256, 0, stream>>>(ei, E, deg, flags);
    k_scan1<<<NB, BW, 0, stream>>>(deg, N, bsum);
    k_scan2<<<1, 1024, 0, stream>>>(bsum, NB, bbase, E);
    k_scan3<<<NB, BW, 0, stream>>>(deg, N, bbase, cursor, dinv, bcur);
    k_fill1<<<eb, 256, 0, stream>>>(ei, E, bcur, bkt, flags);
    k_fill2<<<NB, 256, 0, stream>>>(bkt, bbase, cursor, N, csr);

    int gb = (N + 31) / 32;
    int ab = (N + 3) / 4;
    // layer 1
    k_gemm1<<<gb, 256, 0, stream>>>(x, W1, dinv, t, N, flags);
    k_agg<true><<<ab, 256, 0, stream>>>(t, csr, cursor, deg, dinv, b1, h, N, flags);
    // layer 2
    k_gemm2<<<gb, 256, 0, stream>>>(h, W2, dinv, t, N, flags);
    k_agg<false><<<ab, 256, 0, stream>>>(t, csr, cursor, deg, dinv, b2, h, N, flags);
    // pool + head
    k_pool<<<G, 64, 0, stream>>>(h, bat, N, pooled, flags);
    k_out<<<G, 64, 0, stream>>>(pooled, Wout, bout, d_out, G, flags);
}

// Round 6
// 325.600 us; speedup vs baseline: 2.8380x; 2.8380x over previous
//
#include <hip/hip_runtime.h>
#include <hip/hip_bf16.h>

#define F_IN 128
#define HID  64
#define NCLS 19
#define BW   128          // nodes per bucket (dst >> 7)
#define NBMAX 512         // max buckets (N <= 65536); also sortA scan width
#define ACAP 6144         // edges per k_sortA block (24 KB LDS)
#define BCAP 8192         // max edges per bucket staged in LDS by k_sortB

// -------- adaptive loads: flags[0]=1 -> floats are fp32 (else bf16)
//          flags[1]=1 -> indices are int64 (else int32)
__device__ __forceinline__ float ldf(const void* p, long i, int fp32) {
    if (fp32) return ((const float*)p)[i];
    return __bfloat162float(((const __hip_bfloat16*)p)[i]);
}
__device__ __forceinline__ int ldi(const void* p, long i, int i64) {
    if (i64) return (int)((const long long*)p)[i];
    return ((const int*)p)[i];
}
__device__ __forceinline__ unsigned short f2bf(float f) {
    __hip_bfloat16 h = __float2bfloat16(f);   // RNE
    unsigned short r;
    __builtin_memcpy(&r, &h, 2);
    return r;
}
__device__ __forceinline__ float bflo(unsigned u) { return __uint_as_float(u << 16); }
__device__ __forceinline__ float bfhi(unsigned u) { return __uint_as_float(u & 0xffff0000u); }

// ---------------- dtype sniffer ----------------
__global__ void k_detect(const void* x, const void* ei, int* flags) {
    if (threadIdx.x != 0) return;
    const unsigned* xw = (const unsigned*)x;
    int bf16 = 1;
    for (int i = 0; i < 16; ++i) {
        unsigned w = xw[i];
        int elo = (w >> 7) & 0xFF;
        int ehi = (w >> 23) & 0xFF;
        if (elo < 100 || elo > 140 || ehi < 100 || ehi > 140) bf16 = 0;
    }
    const unsigned* iw = (const unsigned*)ei;
    int i64 = 1; unsigned anyev = 0;
    for (int k = 0; k < 8; ++k) {
        if (iw[2 * k + 1] != 0) i64 = 0;
        anyev |= iw[2 * k];
    }
    if (anyev == 0) i64 = 0;
    flags[0] = bf16 ? 0 : 1;
    flags[1] = i64;
}

// ---------------- bucket histogram: LDS per block, merged once ----------------
__global__ __launch_bounds__(256) void k_hist(const void* __restrict__ ei, int E, int nbuck,
                                              int* __restrict__ bsum,
                                              const int* __restrict__ flags) {
    __shared__ int lh[NBMAX];
    int i64 = flags[1];
    int t = threadIdx.x;
    lh[t] = 0; lh[t + 256] = 0;
    __syncthreads();
    int chunk = (E + gridDim.x - 1) / gridDim.x;
    int e0 = blockIdx.x * chunk;
    int e1 = min(E, e0 + chunk);
    for (int e = e0 + t; e < e1; e += 256)
        atomicAdd(&lh[(ldi(ei, (long)E + e, i64) >> 7) & (NBMAX - 1)], 1);
    __syncthreads();
    for (int b = t; b < nbuck; b += 256)
        if (lh[b]) atomicAdd(&bsum[b], lh[b]);
}

// ---------------- scan bucket sums -> bbase (exclusive), init bcur ----------------
__global__ __launch_bounds__(1024) void k_scan2(const int* __restrict__ bsum, int NB,
                                                int* __restrict__ bbase,
                                                int* __restrict__ bcur, int E) {
    __shared__ int s[1024];
    int t = threadIdx.x;
    int v = (t < NB) ? bsum[t] : 0;
    s[t] = v;
    __syncthreads();
    for (int off = 1; off < 1024; off <<= 1) {
        int x = (t >= off) ? s[t - off] : 0;
        __syncthreads();
        s[t] += x;
        __syncthreads();
    }
    if (t < NB) { bbase[t] = s[t] - v; bcur[t] = s[t] - v; }
    if (t == 0) bbase[NB] = E;
}

// ---------------- sort pass A: per-chunk LDS counting sort by bucket ----------------
// 512 threads, ONE scan slot per thread (no dual-slot trickery).
__global__ __launch_bounds__(512) void k_sortA(const void* __restrict__ ei, int E, int nbuck,
                                               int* bcur, int* __restrict__ bkt,
                                               const int* __restrict__ flags) {
    __shared__ int lbuf[ACAP];
    __shared__ int lh[NBMAX];
    __shared__ int lsc[NBMAX];
    __shared__ int lcur[NBMAX];
    __shared__ int gbase[NBMAX];
    int i64 = flags[1];
    int t = threadIdx.x;                 // 0..511
    int e0 = blockIdx.x * ACAP;
    int e1 = min(E, e0 + ACAP);
    int cnt = e1 - e0;
    lh[t] = 0;
    __syncthreads();
    for (int e = e0 + t; e < e1; e += 512)
        atomicAdd(&lh[(ldi(ei, (long)E + e, i64) >> 7) & (NBMAX - 1)], 1);
    __syncthreads();
    int v = lh[t];
    lsc[t] = v;
    __syncthreads();
    for (int off = 1; off < 512; off <<= 1) {        // Hillis-Steele inclusive
        int a = (t >= off) ? lsc[t - off] : 0;
        __syncthreads();
        lsc[t] += a;
        __syncthreads();
    }
    int ex = lsc[t] - v;                 // own-slot read; exclusive prefix
    lsc[t] = ex;
    lcur[t] = ex;
    gbase[t] = (v && t < nbuck) ? atomicAdd(&bcur[t], v) : 0;
    __syncthreads();
    // scatter into LDS by local rank
    for (int e = e0 + t; e < e1; e += 512) {
        int s = ldi(ei, e, i64);
        int d = ldi(ei, (long)E + e, i64);
        int r = atomicAdd(&lcur[(d >> 7) & (NBMAX - 1)], 1);
        r = min(max(r, 0), ACAP - 1);
        lbuf[r] = (s << 7) | (d & (BW - 1));
    }
    __syncthreads();
    // coalesced writeout: slot i -> bucket via binary search over exclusive bounds
    for (int i = t; i < cnt; i += 512) {
        int lo = 0, hi = nbuck;
        while (hi - lo > 1) {
            int mid = (lo + hi) >> 1;
            if (lsc[mid] <= i) lo = mid; else hi = mid;
        }
        long idx = (long)gbase[lo] + (i - lsc[lo]);
        if (idx >= 0 && idx < E) bkt[idx] = lbuf[i];
    }
}

// ---------------- sort pass B: per-bucket LDS counting sort -> csr, cursor, deg, dinv ----------------
__global__ __launch_bounds__(256) void k_sortB(const int* __restrict__ bkt,
                                               const int* __restrict__ bbase,
                                               int N, int E,
                                               int* __restrict__ csr,
                                               int* __restrict__ cursor,
                                               int* __restrict__ deg,
                                               float* __restrict__ dinv) {
    __shared__ int lcsr[BCAP];
    __shared__ int lh[BW], lsc[BW], lcur[BW];
    int b = blockIdx.x, t = threadIdx.x;
    int base = bbase[b], end = bbase[b + 1];
    base = min(max(base, 0), E);
    end  = min(max(end, base), E);
    int cnt = end - base;
    if (t < BW) lh[t] = 0;
    __syncthreads();
    for (int i = base + t; i < end; i += 256)
        atomicAdd(&lh[bkt[i] & (BW - 1)], 1);
    __syncthreads();
    if (t < BW) lsc[t] = lh[t];
    __syncthreads();
    for (int off = 1; off < BW; off <<= 1) {
        int a = (t < BW && t >= off) ? lsc[t - off] : 0;
        __syncthreads();
        if (t < BW) lsc[t] += a;
        __syncthreads();
    }
    if (t < BW) {
        int ex = lsc[t] - lh[t];
        lcur[t] = ex;
        int n = b * BW + t;
        if (n < N) {
            cursor[n] = base + ex;
            deg[n] = lh[t];
            dinv[n] = rsqrtf((float)(lh[t] + 1));   // +1 self-loop
        }
    }
    __syncthreads();
    bool fits = (cnt <= BCAP);
    for (int i = base + t; i < end; i += 256) {
        int w = bkt[i];
        int r = atomicAdd(&lcur[w & (BW - 1)], 1);
        int sv = (int)((unsigned)w >> 7);           // unsigned shift: never negative
        if (sv >= N) sv = 0;                        // poison guard
        if (fits) { r = min(max(r, 0), BCAP - 1); lcsr[r] = sv; }
        else { long idx = (long)base + r; if (idx >= 0 && idx < E) csr[idx] = sv; }
    }
    __syncthreads();
    if (fits)
        for (int i = t; i < cnt; i += 256) csr[base + i] = lcsr[i];
}

// ---------------- GEMM1: t[i,:] = bf16(dinv[i] * (x[i,:] @ W1)) ----------------
__global__ __launch_bounds__(256) void k_gemm1(const void* __restrict__ x,
                                               const void* __restrict__ W,
                                               const float* __restrict__ dinv,
                                               unsigned short* __restrict__ t, int N,
                                               const int* __restrict__ flags) {
    __shared__ __align__(16) float wl[F_IN * HID];   // 32 KB
    __shared__ __align__(16) float xl[32 * F_IN];    // 16 KB
    int fp32 = flags[0];
    int tid = threadIdx.x;
    for (int i = tid; i < F_IN * HID; i += 256) wl[i] = ldf(W, i, fp32);
    int row0 = blockIdx.x * 32;
    for (int i = tid; i < 32 * F_IN; i += 256) {
        int r = row0 + (i >> 7);
        xl[i] = (r < N) ? ldf(x, (long)r * F_IN + (i & 127), fp32) : 0.f;
    }
    __syncthreads();
    int w = tid >> 6, j = tid & 63;
    float acc[8];
#pragma unroll
    for (int r = 0; r < 8; ++r) acc[r] = 0.f;
    const float4* x4 = (const float4*)(xl + w * 8 * F_IN);
#pragma unroll 2
    for (int k = 0; k < F_IN; k += 4) {
        float wv0 = wl[k * HID + j];
        float wv1 = wl[(k + 1) * HID + j];
        float wv2 = wl[(k + 2) * HID + j];
        float wv3 = wl[(k + 3) * HID + j];
#pragma unroll
        for (int r = 0; r < 8; ++r) {
            float4 xv = x4[(r * F_IN + k) >> 2];
            acc[r] += xv.x * wv0;
            acc[r] += xv.y * wv1;
            acc[r] += xv.z * wv2;
            acc[r] += xv.w * wv3;
        }
    }
#pragma unroll
    for (int r = 0; r < 8; ++r) {
        int row = row0 + w * 8 + r;
        if (row < N) t[(size_t)row * HID + j] = f2bf(dinv[row] * acc[r]);
    }
}

// ---------------- GEMM2: t[i,:] = bf16(dinv[i] * (h[i,:] @ W2)), h bf16 ----------------
__global__ __launch_bounds__(256) void k_gemm2(const unsigned short* __restrict__ h,
                                               const void* __restrict__ W,
                                               const float* __restrict__ dinv,
                                               unsigned short* __restrict__ t, int N,
                                               const int* __restrict__ flags) {
    __shared__ __align__(16) float wl[HID * HID];   // 16 KB
    __shared__ __align__(16) float xl[32 * HID];    // 8 KB
    int fp32 = flags[0];
    int tid = threadIdx.x;
    for (int i = tid; i < HID * HID; i += 256) wl[i] = ldf(W, i, fp32);
    int row0 = blockIdx.x * 32;
    for (int i = tid; i < 32 * HID; i += 256) {
        int r = row0 + (i >> 6);
        xl[i] = (r < N) ? bflo((unsigned)h[(size_t)r * HID + (i & 63)]) : 0.f;
    }
    __syncthreads();
    int w = tid >> 6, j = tid & 63;
    float acc[8];
#pragma unroll
    for (int r = 0; r < 8; ++r) acc[r] = 0.f;
    const float4* x4 = (const float4*)(xl + w * 8 * HID);
#pragma unroll 2
    for (int k = 0; k < HID; k += 4) {
        float wv0 = wl[k * HID + j];
        float wv1 = wl[(k + 1) * HID + j];
        float wv2 = wl[(k + 2) * HID + j];
        float wv3 = wl[(k + 3) * HID + j];
#pragma unroll
        for (int r = 0; r < 8; ++r) {
            float4 xv = x4[(r * HID + k) >> 2];
            acc[r] += xv.x * wv0;
            acc[r] += xv.y * wv1;
            acc[r] += xv.z * wv2;
            acc[r] += xv.w * wv3;
        }
    }
#pragma unroll
    for (int r = 0; r < 8; ++r) {
        int row = row0 + w * 8 + r;
        if (row < N) t[(size_t)row * HID + j] = f2bf(dinv[row] * acc[r]);
    }
}

// ---------------- aggregation: one wave per node, 4 row-gathers in flight ----------------
template <bool RELU>
__global__ __launch_bounds__(256) void k_agg(const unsigned short* __restrict__ t,
                                             const int* __restrict__ csr,
                                             const int* __restrict__ cursor,
                                             const int* __restrict__ deg,
                                             const float* __restrict__ dinv,
                                             const void* __restrict__ bias,
                                             unsigned short* __restrict__ out,
                                             int N, int E, const int* __restrict__ flags) {
    int node = blockIdx.x * 4 + (threadIdx.x >> 6);
    if (node >= N) return;
    int lane = threadIdx.x & 63;
    int g = lane >> 4;          // neighbor group 0..3
    int l4 = (lane & 15) * 4;   // this lane's 4 features
    int beg = cursor[node];
    int dg = deg[node];
    beg = min(max(beg, 0), E);
    int end = beg + min(max(dg, 0), E - beg);
    float a0 = 0.f, a1 = 0.f, a2 = 0.f, a3 = 0.f;
    for (int e = beg; e < end; e += 16) {
        int i0 = e + g, i1 = e + 4 + g, i2 = e + 8 + g, i3 = e + 12 + g;
        int s0 = csr[i0 < end ? i0 : end - 1];
        int s1 = csr[i1 < end ? i1 : end - 1];
        int s2 = csr[i2 < end ? i2 : end - 1];
        int s3 = csr[i3 < end ? i3 : end - 1];
        s0 = ((unsigned)s0 < (unsigned)N) ? s0 : 0;
        s1 = ((unsigned)s1 < (unsigned)N) ? s1 : 0;
        s2 = ((unsigned)s2 < (unsigned)N) ? s2 : 0;
        s3 = ((unsigned)s3 < (unsigned)N) ? s3 : 0;
        uint2 v0 = *(const uint2*)(t + s0 * HID + l4);
        uint2 v1 = *(const uint2*)(t + s1 * HID + l4);
        uint2 v2 = *(const uint2*)(t + s2 * HID + l4);
        uint2 v3 = *(const uint2*)(t + s3 * HID + l4);
        if (i0 < end) { a0 += bflo(v0.x); a1 += bfhi(v0.x); a2 += bflo(v0.y); a3 += bfhi(v0.y); }
        if (i1 < end) { a0 += bflo(v1.x); a1 += bfhi(v1.x); a2 += bflo(v1.y); a3 += bfhi(v1.y); }
        if (i2 < end) { a0 += bflo(v2.x); a1 += bfhi(v2.x); a2 += bflo(v2.y); a3 += bfhi(v2.y); }
        if (i3 < end) { a0 += bflo(v3.x); a1 += bfhi(v3.x); a2 += bflo(v3.y); a3 += bfhi(v3.y); }
    }
    a0 += __shfl_xor(a0, 16); a0 += __shfl_xor(a0, 32);
    a1 += __shfl_xor(a1, 16); a1 += __shfl_xor(a1, 32);
    a2 += __shfl_xor(a2, 16); a2 += __shfl_xor(a2, 32);
    a3 += __shfl_xor(a3, 16); a3 += __shfl_xor(a3, 32);
    // self-loop
    uint2 sv = *(const uint2*)(t + node * HID + l4);
    a0 += bflo(sv.x); a1 += bfhi(sv.x);
    a2 += bflo(sv.y); a3 += bfhi(sv.y);
    int fp32 = flags[0];
    float di = dinv[node];
    float v0 = di * a0 + ldf(bias, l4 + 0, fp32);
    float v1 = di * a1 + ldf(bias, l4 + 1, fp32);
    float v2 = di * a2 + ldf(bias, l4 + 2, fp32);
    float v3 = di * a3 + ldf(bias, l4 + 3, fp32);
    if (RELU) {
        v0 = fmaxf(v0, 0.f); v1 = fmaxf(v1, 0.f);
        v2 = fmaxf(v2, 0.f); v3 = fmaxf(v3, 0.f);
    }
    if (g == 0) {
        uint2 pk;
        pk.x = (unsigned)f2bf(v0) | ((unsigned)f2bf(v1) << 16);
        pk.y = (unsigned)f2bf(v2) | ((unsigned)f2bf(v3) << 16);
        *(uint2*)(out + node * HID + l4) = pk;
    }
}

// ---------------- mean pool: batch sorted -> per-graph segment mean, atomic-free ----------------
__global__ __launch_bounds__(64) void k_pool(const unsigned short* __restrict__ h2,
                                             const void* __restrict__ batch, int N,
                                             float* __restrict__ pooled,
                                             const int* __restrict__ flags) {
    int g = blockIdx.x;
    int i64 = flags[1];
    int lo = 0, hi = N;
    while (lo < hi) { int mid = (lo + hi) >> 1; if (ldi(batch, mid, i64) < g) lo = mid + 1; else hi = mid; }
    int start = lo;
    hi = N;
    while (lo < hi) { int mid = (lo + hi) >> 1; if (ldi(batch, mid, i64) < g + 1) lo = mid + 1; else hi = mid; }
    int endg = lo;
    int lane = threadIdx.x;
    int half = lane >> 5;
    int l = lane & 31;
    float s0 = 0.f, s1 = 0.f;
    for (int r = start; r < endg; r += 4) {
        int r0 = r + half;
        int r1 = r + 2 + half;
        unsigned u0 = (r0 < endg) ? *(const unsigned*)(h2 + (size_t)r0 * HID + 2 * l) : 0u;
        unsigned u1 = (r1 < endg) ? *(const unsigned*)(h2 + (size_t)r1 * HID + 2 * l) : 0u;
        s0 += bflo(u0) + bflo(u1);
        s1 += bfhi(u0) + bfhi(u1);
    }
    s0 += __shfl_xor(s0, 32);
    s1 += __shfl_xor(s1, 32);
    if (lane < 32) {
        float inv = 1.f / fmaxf((float)(endg - start), 1.f);
        *(float2*)(pooled + (size_t)g * HID + 2 * l) = make_float2(s0 * inv, s1 * inv);
    }
}

// ---------------- head: out[g,:] = pooled[g,:] @ W_out + b_out ----------------
__global__ __launch_bounds__(64) void k_out(const float* __restrict__ pooled,
                                            const void* __restrict__ Wout,
                                            const void* __restrict__ bout,
                                            void* __restrict__ out, int G,
                                            const int* __restrict__ flags) {
    __shared__ float pr[HID];
    int fp32 = flags[0];
    int g = blockIdx.x;
    int tid = threadIdx.x;
    pr[tid] = pooled[(size_t)g * HID + tid];
    __syncthreads();
    if (tid < NCLS) {
        float acc = ldf(bout, tid, fp32);
#pragma unroll 4
        for (int k = 0; k < HID; ++k)
            acc += pr[k] * ldf(Wout, k * NCLS + tid, fp32);
        if (fp32) ((float*)out)[g * NCLS + tid] = acc;
        else ((__hip_bfloat16*)out)[g * NCLS + tid] = __float2bfloat16(acc);
    }
}

extern "C" void kernel_launch(void* const* d_in, const int* in_sizes, int n_in,
                              void* d_out, int out_size, void* d_ws, size_t ws_size,
                              hipStream_t stream) {
    const void* x    = d_in[0];
    const void* ei   = d_in[1];
    const void* bat  = d_in[2];
    const void* W1   = d_in[3];
    const void* b1   = d_in[4];
    const void* W2   = d_in[5];
    const void* b2   = d_in[6];
    const void* Wout = d_in[7];
    const void* bout = d_in[8];

    const int N = in_sizes[0] / F_IN;
    const int E = in_sizes[1] / 2;
    const int G = out_size / NCLS;
    const int NB = (N + BW - 1) / BW;   // < NBMAX

    char* ws = (char*)d_ws;
    size_t off = 0;
    auto carve = [&](size_t bytes) -> void* {
        void* p = ws + off;
        off = (off + bytes + 255) & ~(size_t)255;
        return p;
    };
    int*            flags  = (int*)carve(64);
    int*            deg    = (int*)carve((size_t)N * 4);
    int*            cursor = (int*)carve((size_t)N * 4);
    float*          dinv   = (float*)carve((size_t)N * 4);
    int*            bsum   = (int*)carve((size_t)NB * 4);
    int*            bbase  = (int*)carve((size_t)(NB + 1) * 4);
    int*            bcur   = (int*)carve((size_t)NB * 4);
    int*            csr    = (int*)carve((size_t)E * 4);
    int*            bkt    = (int*)carve((size_t)E * 4);
    unsigned short* t      = (unsigned short*)carve((size_t)N * HID * 2);
    unsigned short* h      = (unsigned short*)carve((size_t)N * HID * 2);
    float*          pooled = (float*)carve((size_t)G * HID * 4);
    (void)ws_size; (void)n_in;

    hipMemsetAsync(bsum, 0, (size_t)NB * 4, stream);

    k_detect<<<1, 64, 0, stream>>>(x, ei, flags);

    // CSR build: hist -> scan -> chunk counting-sort -> bucket counting-sort
    k_hist<<<256, 256, 0, stream>>>(ei, E, NB, bsum, flags);
    k_scan2<<<1, 1024, 0, stream>>>(bsum, NB, bbase, bcur, E);
    int na = (E + ACAP - 1) / ACAP;
    k_sortA<<<na, 512, 0, stream>>>(ei, E, NB, bcur, bkt, flags);
    k_sortB<<<NB, 256, 0, stream>>>(bkt, bbase, N, E, csr, cursor, deg, dinv);

    int gb = (N + 31) / 32;
    int ab = (N + 3) / 4;
    // layer 1
    k_gemm1<<<gb, 256, 0, stream>>>(x, W1, dinv, t, N, flags);
    k_agg<true><<<ab, 256, 0, stream>>>(t, csr, cursor, deg, dinv, b1, h, N, E, flags);
    // layer 2
    k_gemm2<<<gb, 256, 0, stream>>>(h, W2, dinv, t, N, flags);
    k_agg<false><<<ab, 256, 0, stream>>>(t, csr, cursor, deg, dinv, b2, h, N, E, flags);
    // pool + head
    k_pool<<<G, 64, 0, stream>>>(h, bat, N, pooled, flags);
    k_out<<<G, 64, 0, stream>>>(pooled, Wout, bout, d_out, G, flags);
}

// Round 7
// 281.932 us; speedup vs baseline: 3.2775x; 1.1549x over previous
//
#include <hip/hip_runtime.h>
#include <hip/hip_bf16.h>

#define F_IN 128
#define HID  64
#define NCLS 19
#define BW   128          // nodes per bucket (dst >> 7)
#define NBMAX 512         // max buckets (N <= 65536); also sortA scan width
#define ACAP 6144         // edges per k_sortA block (24 KB LDS)
#define BCAP 8192         // max edges per bucket staged in LDS by k_sortB
#define W1STR 136         // padded LDS stride (shorts) for W1^T rows (128+8, 16B-aligned)
#define W2STR 72          // padded LDS stride (shorts) for W2^T rows (64+8, 16B-aligned)

typedef __bf16 bf16x8 __attribute__((ext_vector_type(8)));
typedef float  f32x4  __attribute__((ext_vector_type(4)));

// -------- adaptive loads: flags[0]=1 -> floats are fp32 (else bf16)
//          flags[1]=1 -> indices are int64 (else int32)
__device__ __forceinline__ float ldf(const void* p, long i, int fp32) {
    if (fp32) return ((const float*)p)[i];
    return __bfloat162float(((const __hip_bfloat16*)p)[i]);
}
__device__ __forceinline__ int ldi(const void* p, long i, int i64) {
    if (i64) return (int)((const long long*)p)[i];
    return ((const int*)p)[i];
}
__device__ __forceinline__ unsigned short f2bf(float f) {
    __hip_bfloat16 h = __float2bfloat16(f);   // RNE
    unsigned short r;
    __builtin_memcpy(&r, &h, 2);
    return r;
}
__device__ __forceinline__ float bflo(unsigned u) { return __uint_as_float(u << 16); }
__device__ __forceinline__ float bfhi(unsigned u) { return __uint_as_float(u & 0xffff0000u); }

// load an 8-element bf16 A/B fragment from 16 contiguous bytes
__device__ __forceinline__ bf16x8 ldfrag(const unsigned short* p) {
    uint4 u = *(const uint4*)p;
    return __builtin_bit_cast(bf16x8, u);
}
// adaptive: bf16 direct, or fp32 -> convert (fallback, wave-uniform branch)
__device__ __forceinline__ bf16x8 ldfrag_any(const void* p, long off, int fp32) {
    if (!fp32) return ldfrag((const unsigned short*)p + off);
    const float* f = (const float*)p + off;
    unsigned short s[8];
#pragma unroll
    for (int i = 0; i < 8; ++i) s[i] = f2bf(f[i]);
    uint4 u = make_uint4((unsigned)s[0] | ((unsigned)s[1] << 16),
                         (unsigned)s[2] | ((unsigned)s[3] << 16),
                         (unsigned)s[4] | ((unsigned)s[5] << 16),
                         (unsigned)s[6] | ((unsigned)s[7] << 16));
    return __builtin_bit_cast(bf16x8, u);
}

// ---------------- dtype sniffer ----------------
__global__ void k_detect(const void* x, const void* ei, int* flags) {
    if (threadIdx.x != 0) return;
    const unsigned* xw = (const unsigned*)x;
    int bf16 = 1;
    for (int i = 0; i < 16; ++i) {
        unsigned w = xw[i];
        int elo = (w >> 7) & 0xFF;
        int ehi = (w >> 23) & 0xFF;
        if (elo < 100 || elo > 140 || ehi < 100 || ehi > 140) bf16 = 0;
    }
    const unsigned* iw = (const unsigned*)ei;
    int i64 = 1; unsigned anyev = 0;
    for (int k = 0; k < 8; ++k) {
        if (iw[2 * k + 1] != 0) i64 = 0;
        anyev |= iw[2 * k];
    }
    if (anyev == 0) i64 = 0;
    flags[0] = bf16 ? 0 : 1;
    flags[1] = i64;
}

// ---------------- bucket histogram: LDS per block, merged once ----------------
__global__ __launch_bounds__(256) void k_hist(const void* __restrict__ ei, int E, int nbuck,
                                              int* __restrict__ bsum,
                                              const int* __restrict__ flags) {
    __shared__ int lh[NBMAX];
    int i64 = flags[1];
    int t = threadIdx.x;
    lh[t] = 0; lh[t + 256] = 0;
    __syncthreads();
    int chunk = (E + gridDim.x - 1) / gridDim.x;
    int e0 = blockIdx.x * chunk;
    int e1 = min(E, e0 + chunk);
    for (int e = e0 + t; e < e1; e += 256)
        atomicAdd(&lh[(ldi(ei, (long)E + e, i64) >> 7) & (NBMAX - 1)], 1);
    __syncthreads();
    for (int b = t; b < nbuck; b += 256)
        if (lh[b]) atomicAdd(&bsum[b], lh[b]);
}

// ---------------- scan bucket sums -> bbase (exclusive), init bcur ----------------
__global__ __launch_bounds__(1024) void k_scan2(const int* __restrict__ bsum, int NB,
                                                int* __restrict__ bbase,
                                                int* __restrict__ bcur, int E) {
    __shared__ int s[1024];
    int t = threadIdx.x;
    int v = (t < NB) ? bsum[t] : 0;
    s[t] = v;
    __syncthreads();
    for (int off = 1; off < 1024; off <<= 1) {
        int x = (t >= off) ? s[t - off] : 0;
        __syncthreads();
        s[t] += x;
        __syncthreads();
    }
    if (t < NB) { bbase[t] = s[t] - v; bcur[t] = s[t] - v; }
    if (t == 0) bbase[NB] = E;
}

// ---------------- sort pass A: per-chunk LDS counting sort by bucket ----------------
__global__ __launch_bounds__(512) void k_sortA(const void* __restrict__ ei, int E, int nbuck,
                                               int* bcur, int* __restrict__ bkt,
                                               const int* __restrict__ flags) {
    __shared__ int lbuf[ACAP];
    __shared__ int lh[NBMAX];
    __shared__ int lsc[NBMAX];
    __shared__ int lcur[NBMAX];
    __shared__ int gbase[NBMAX];
    int i64 = flags[1];
    int t = threadIdx.x;                 // 0..511
    int e0 = blockIdx.x * ACAP;
    int e1 = min(E, e0 + ACAP);
    int cnt = e1 - e0;
    lh[t] = 0;
    __syncthreads();
    for (int e = e0 + t; e < e1; e += 512)
        atomicAdd(&lh[(ldi(ei, (long)E + e, i64) >> 7) & (NBMAX - 1)], 1);
    __syncthreads();
    int v = lh[t];
    lsc[t] = v;
    __syncthreads();
    for (int off = 1; off < 512; off <<= 1) {        // Hillis-Steele inclusive
        int a = (t >= off) ? lsc[t - off] : 0;
        __syncthreads();
        lsc[t] += a;
        __syncthreads();
    }
    int ex = lsc[t] - v;                 // exclusive prefix
    lsc[t] = ex;
    lcur[t] = ex;
    gbase[t] = (v && t < nbuck) ? atomicAdd(&bcur[t], v) : 0;
    __syncthreads();
    for (int e = e0 + t; e < e1; e += 512) {
        int s = ldi(ei, e, i64);
        int d = ldi(ei, (long)E + e, i64);
        int r = atomicAdd(&lcur[(d >> 7) & (NBMAX - 1)], 1);
        r = min(max(r, 0), ACAP - 1);
        lbuf[r] = (s << 7) | (d & (BW - 1));
    }
    __syncthreads();
    for (int i = t; i < cnt; i += 512) {
        int lo = 0, hi = nbuck;
        while (hi - lo > 1) {
            int mid = (lo + hi) >> 1;
            if (lsc[mid] <= i) lo = mid; else hi = mid;
        }
        long idx = (long)gbase[lo] + (i - lsc[lo]);
        if (idx >= 0 && idx < E) bkt[idx] = lbuf[i];
    }
}

// ---------------- sort pass B: per-bucket LDS counting sort -> csr, cursor, deg, dinv ----------------
__global__ __launch_bounds__(256) void k_sortB(const int* __restrict__ bkt,
                                               const int* __restrict__ bbase,
                                               int N, int E,
                                               int* __restrict__ csr,
                                               int* __restrict__ cursor,
                                               int* __restrict__ deg,
                                               float* __restrict__ dinv) {
    __shared__ int lcsr[BCAP];
    __shared__ int lh[BW], lsc[BW], lcur[BW];
    int b = blockIdx.x, t = threadIdx.x;
    int base = bbase[b], end = bbase[b + 1];
    base = min(max(base, 0), E);
    end  = min(max(end, base), E);
    int cnt = end - base;
    if (t < BW) lh[t] = 0;
    __syncthreads();
    for (int i = base + t; i < end; i += 256)
        atomicAdd(&lh[bkt[i] & (BW - 1)], 1);
    __syncthreads();
    if (t < BW) lsc[t] = lh[t];
    __syncthreads();
    for (int off = 1; off < BW; off <<= 1) {
        int a = (t < BW && t >= off) ? lsc[t - off] : 0;
        __syncthreads();
        if (t < BW) lsc[t] += a;
        __syncthreads();
    }
    if (t < BW) {
        int ex = lsc[t] - lh[t];
        lcur[t] = ex;
        int n = b * BW + t;
        if (n < N) {
            cursor[n] = base + ex;
            deg[n] = lh[t];
            dinv[n] = rsqrtf((float)(lh[t] + 1));   // +1 self-loop
        }
    }
    __syncthreads();
    bool fits = (cnt <= BCAP);
    for (int i = base + t; i < end; i += 256) {
        int w = bkt[i];
        int r = atomicAdd(&lcur[w & (BW - 1)], 1);
        int sv = (int)((unsigned)w >> 7);
        if (sv >= N) sv = 0;                        // poison guard
        if (fits) { r = min(max(r, 0), BCAP - 1); lcsr[r] = sv; }
        else { long idx = (long)base + r; if (idx >= 0 && idx < E) csr[idx] = sv; }
    }
    __syncthreads();
    if (fits)
        for (int i = t; i < cnt; i += 256) csr[base + i] = lcsr[i];
}

// ---------------- GEMM1 (MFMA): t[i,:] = bf16(dinv[i] * (x[i,:] @ W1)) ----------------
// block = 256 thr (4 waves), 64 rows/block (16 rows/wave). A-frags direct from
// global (x is row-major bf16: lane's frag = 16 contiguous bytes). W1^T staged
// in LDS once/block. C/D layout: col=lane&15, row=(lane>>4)*4+reg [m89/m91].
__global__ __launch_bounds__(256) void k_gemm1(const void* __restrict__ x,
                                               const void* __restrict__ W,
                                               const float* __restrict__ dinv,
                                               unsigned short* __restrict__ t, int N,
                                               const int* __restrict__ flags) {
    __shared__ __align__(16) unsigned short wt[HID * W1STR];   // W1^T, padded
    int fp32 = flags[0];
    int tid = threadIdx.x;
    // stage W1^T: wt[n][k] = W1[k][n]
    for (int i = tid; i < F_IN * HID; i += 256) {
        int n = i >> 7, k = i & 127;
        wt[n * W1STR + k] = f2bf(ldf(W, (long)k * HID + n, fp32));
    }
    __syncthreads();
    int wv = tid >> 6, lane = tid & 63;
    int quad = lane >> 4, l16 = lane & 15;
    int r0 = blockIdx.x * 64 + wv * 16;
    int rowA = min(r0 + l16, N - 1);
    bf16x8 a[4];
#pragma unroll
    for (int kq = 0; kq < 4; ++kq)
        a[kq] = ldfrag_any(x, (long)rowA * F_IN + kq * 32 + quad * 8, fp32);
    float di[4];
    int rowC = r0 + quad * 4;
#pragma unroll
    for (int r = 0; r < 4; ++r) di[r] = (rowC + r < N) ? dinv[rowC + r] : 0.f;
#pragma unroll
    for (int cg = 0; cg < 4; ++cg) {
        int col = cg * 16 + l16;
        f32x4 acc = {0.f, 0.f, 0.f, 0.f};
#pragma unroll
        for (int kq = 0; kq < 4; ++kq) {
            bf16x8 b = ldfrag(wt + col * W1STR + kq * 32 + quad * 8);
            acc = __builtin_amdgcn_mfma_f32_16x16x32_bf16(a[kq], b, acc, 0, 0, 0);
        }
#pragma unroll
        for (int r = 0; r < 4; ++r) {
            int row = rowC + r;
            if (row < N) t[(size_t)row * HID + col] = f2bf(di[r] * acc[r]);
        }
    }
}

// ---------------- GEMM2 (MFMA): t[i,:] = bf16(dinv[i] * (h[i,:] @ W2)), h bf16 ----------------
__global__ __launch_bounds__(256) void k_gemm2(const unsigned short* __restrict__ h,
                                               const void* __restrict__ W,
                                               const float* __restrict__ dinv,
                                               unsigned short* __restrict__ t, int N,
                                               const int* __restrict__ flags) {
    __shared__ __align__(16) unsigned short wt[HID * W2STR];   // W2^T, padded
    int fp32 = flags[0];
    int tid = threadIdx.x;
    for (int i = tid; i < HID * HID; i += 256) {
        int n = i >> 6, k = i & 63;
        wt[n * W2STR + k] = f2bf(ldf(W, (long)k * HID + n, fp32));
    }
    __syncthreads();
    int wv = tid >> 6, lane = tid & 63;
    int quad = lane >> 4, l16 = lane & 15;
    int r0 = blockIdx.x * 64 + wv * 16;
    int rowA = min(r0 + l16, N - 1);
    bf16x8 a[2];
#pragma unroll
    for (int kq = 0; kq < 2; ++kq)
        a[kq] = ldfrag(h + (size_t)rowA * HID + kq * 32 + quad * 8);
    float di[4];
    int rowC = r0 + quad * 4;
#pragma unroll
    for (int r = 0; r < 4; ++r) di[r] = (rowC + r < N) ? dinv[rowC + r] : 0.f;
#pragma unroll
    for (int cg = 0; cg < 4; ++cg) {
        int col = cg * 16 + l16;
        f32x4 acc = {0.f, 0.f, 0.f, 0.f};
#pragma unroll
        for (int kq = 0; kq < 2; ++kq) {
            bf16x8 b = ldfrag(wt + col * W2STR + kq * 32 + quad * 8);
            acc = __builtin_amdgcn_mfma_f32_16x16x32_bf16(a[kq], b, acc, 0, 0, 0);
        }
#pragma unroll
        for (int r = 0; r < 4; ++r) {
            int row = rowC + r;
            if (row < N) t[(size_t)row * HID + col] = f2bf(di[r] * acc[r]);
        }
    }
}

// ---------------- aggregation: one wave per node, 4 row-gathers in flight ----------------
template <bool RELU>
__global__ __launch_bounds__(256) void k_agg(const unsigned short* __restrict__ t,
                                             const int* __restrict__ csr,
                                             const int* __restrict__ cursor,
                                             const int* __restrict__ deg,
                                             const float* __restrict__ dinv,
                                             const void* __restrict__ bias,
                                             unsigned short* __restrict__ out,
                                             int N, int E, const int* __restrict__ flags) {
    int node = blockIdx.x * 4 + (threadIdx.x >> 6);
    if (node >= N) return;
    int lane = threadIdx.x & 63;
    int g = lane >> 4;          // neighbor group 0..3
    int l4 = (lane & 15) * 4;   // this lane's 4 features
    int beg = cursor[node];
    int dg = deg[node];
    beg = min(max(beg, 0), E);
    int end = beg + min(max(dg, 0), E - beg);
    float a0 = 0.f, a1 = 0.f, a2 = 0.f, a3 = 0.f;
    for (int e = beg; e < end; e += 16) {
        int i0 = e + g, i1 = e + 4 + g, i2 = e + 8 + g, i3 = e + 12 + g;
        int s0 = csr[i0 < end ? i0 : end - 1];
        int s1 = csr[i1 < end ? i1 : end - 1];
        int s2 = csr[i2 < end ? i2 : end - 1];
        int s3 = csr[i3 < end ? i3 : end - 1];
        s0 = ((unsigned)s0 < (unsigned)N) ? s0 : 0;
        s1 = ((unsigned)s1 < (unsigned)N) ? s1 : 0;
        s2 = ((unsigned)s2 < (unsigned)N) ? s2 : 0;
        s3 = ((unsigned)s3 < (unsigned)N) ? s3 : 0;
        uint2 v0 = *(const uint2*)(t + s0 * HID + l4);
        uint2 v1 = *(const uint2*)(t + s1 * HID + l4);
        uint2 v2 = *(const uint2*)(t + s2 * HID + l4);
        uint2 v3 = *(const uint2*)(t + s3 * HID + l4);
        if (i0 < end) { a0 += bflo(v0.x); a1 += bfhi(v0.x); a2 += bflo(v0.y); a3 += bfhi(v0.y); }
        if (i1 < end) { a0 += bflo(v1.x); a1 += bfhi(v1.x); a2 += bflo(v1.y); a3 += bfhi(v1.y); }
        if (i2 < end) { a0 += bflo(v2.x); a1 += bfhi(v2.x); a2 += bflo(v2.y); a3 += bfhi(v2.y); }
        if (i3 < end) { a0 += bflo(v3.x); a1 += bfhi(v3.x); a2 += bflo(v3.y); a3 += bfhi(v3.y); }
    }
    a0 += __shfl_xor(a0, 16); a0 += __shfl_xor(a0, 32);
    a1 += __shfl_xor(a1, 16); a1 += __shfl_xor(a1, 32);
    a2 += __shfl_xor(a2, 16); a2 += __shfl_xor(a2, 32);
    a3 += __shfl_xor(a3, 16); a3 += __shfl_xor(a3, 32);
    // self-loop
    uint2 sv = *(const uint2*)(t + node * HID + l4);
    a0 += bflo(sv.x); a1 += bfhi(sv.x);
    a2 += bflo(sv.y); a3 += bfhi(sv.y);
    int fp32 = flags[0];
    float di = dinv[node];
    float v0 = di * a0 + ldf(bias, l4 + 0, fp32);
    float v1 = di * a1 + ldf(bias, l4 + 1, fp32);
    float v2 = di * a2 + ldf(bias, l4 + 2, fp32);
    float v3 = di * a3 + ldf(bias, l4 + 3, fp32);
    if (RELU) {
        v0 = fmaxf(v0, 0.f); v1 = fmaxf(v1, 0.f);
        v2 = fmaxf(v2, 0.f); v3 = fmaxf(v3, 0.f);
    }
    if (g == 0) {
        uint2 pk;
        pk.x = (unsigned)f2bf(v0) | ((unsigned)f2bf(v1) << 16);
        pk.y = (unsigned)f2bf(v2) | ((unsigned)f2bf(v3) << 16);
        *(uint2*)(out + node * HID + l4) = pk;
    }
}

// ---------------- mean pool: batch sorted -> per-graph segment mean, atomic-free ----------------
__global__ __launch_bounds__(64) void k_pool(const unsigned short* __restrict__ h2,
                                             const void* __restrict__ batch, int N,
                                             float* __restrict__ pooled,
                                             const int* __restrict__ flags) {
    int g = blockIdx.x;
    int i64 = flags[1];
    int lo = 0, hi = N;
    while (lo < hi) { int mid = (lo + hi) >> 1; if (ldi(batch, mid, i64) < g) lo = mid + 1; else hi = mid; }
    int start = lo;
    hi = N;
    while (lo < hi) { int mid = (lo + hi) >> 1; if (ldi(batch, mid, i64) < g + 1) lo = mid + 1; else hi = mid; }
    int endg = lo;
    int lane = threadIdx.x;
    int half = lane >> 5;
    int l = lane & 31;
    float s0 = 0.f, s1 = 0.f;
    for (int r = start; r < endg; r += 4) {
        int r0 = r + half;
        int r1 = r + 2 + half;
        unsigned u0 = (r0 < endg) ? *(const unsigned*)(h2 + (size_t)r0 * HID + 2 * l) : 0u;
        unsigned u1 = (r1 < endg) ? *(const unsigned*)(h2 + (size_t)r1 * HID + 2 * l) : 0u;
        s0 += bflo(u0) + bflo(u1);
        s1 += bfhi(u0) + bfhi(u1);
    }
    s0 += __shfl_xor(s0, 32);
    s1 += __shfl_xor(s1, 32);
    if (lane < 32) {
        float inv = 1.f / fmaxf((float)(endg - start), 1.f);
        *(float2*)(pooled + (size_t)g * HID + 2 * l) = make_float2(s0 * inv, s1 * inv);
    }
}

// ---------------- head: out[g,:] = pooled[g,:] @ W_out + b_out ----------------
__global__ __launch_bounds__(64) void k_out(const float* __restrict__ pooled,
                                            const void* __restrict__ Wout,
                                            const void* __restrict__ bout,
                                            void* __restrict__ out, int G,
                                            const int* __restrict__ flags) {
    __shared__ float pr[HID];
    int fp32 = flags[0];
    int g = blockIdx.x;
    int tid = threadIdx.x;
    pr[tid] = pooled[(size_t)g * HID + tid];
    __syncthreads();
    if (tid < NCLS) {
        float acc = ldf(bout, tid, fp32);
#pragma unroll 4
        for (int k = 0; k < HID; ++k)
            acc += pr[k] * ldf(Wout, k * NCLS + tid, fp32);
        if (fp32) ((float*)out)[g * NCLS + tid] = acc;
        else ((__hip_bfloat16*)out)[g * NCLS + tid] = __float2bfloat16(acc);
    }
}

extern "C" void kernel_launch(void* const* d_in, const int* in_sizes, int n_in,
                              void* d_out, int out_size, void* d_ws, size_t ws_size,
                              hipStream_t stream) {
    const void* x    = d_in[0];
    const void* ei   = d_in[1];
    const void* bat  = d_in[2];
    const void* W1   = d_in[3];
    const void* b1   = d_in[4];
    const void* W2   = d_in[5];
    const void* b2   = d_in[6];
    const void* Wout = d_in[7];
    const void* bout = d_in[8];

    const int N = in_sizes[0] / F_IN;
    const int E = in_sizes[1] / 2;
    const int G = out_size / NCLS;
    const int NB = (N + BW - 1) / BW;   // < NBMAX

    char* ws = (char*)d_ws;
    size_t off = 0;
    auto carve = [&](size_t bytes) -> void* {
        void* p = ws + off;
        off = (off + bytes + 255) & ~(size_t)255;
        return p;
    };
    int*            flags  = (int*)carve(64);
    int*            deg    = (int*)carve((size_t)N * 4);
    int*            cursor = (int*)carve((size_t)N * 4);
    float*          dinv   = (float*)carve((size_t)N * 4);
    int*            bsum   = (int*)carve((size_t)NB * 4);
    int*            bbase  = (int*)carve((size_t)(NB + 1) * 4);
    int*            bcur   = (int*)carve((size_t)NB * 4);
    int*            csr    = (int*)carve((size_t)E * 4);
    int*            bkt    = (int*)carve((size_t)E * 4);
    unsigned short* t      = (unsigned short*)carve((size_t)N * HID * 2);
    unsigned short* h      = (unsigned short*)carve((size_t)N * HID * 2);
    float*          pooled = (float*)carve((size_t)G * HID * 4);
    (void)ws_size; (void)n_in;

    hipMemsetAsync(bsum, 0, (size_t)NB * 4, stream);

    k_detect<<<1, 64, 0, stream>>>(x, ei, flags);

    // CSR build: hist -> scan -> chunk counting-sort -> bucket counting-sort
    k_hist<<<256, 256, 0, stream>>>(ei, E, NB, bsum, flags);
    k_scan2<<<1, 1024, 0, stream>>>(bsum, NB, bbase, bcur, E);
    int na = (E + ACAP - 1) / ACAP;
    k_sortA<<<na, 512, 0, stream>>>(ei, E, NB, bcur, bkt, flags);
    k_sortB<<<NB, 256, 0, stream>>>(bkt, bbase, N, E, csr, cursor, deg, dinv);

    int gb = (N + 63) / 64;
    int ab = (N + 3) / 4;
    // layer 1
    k_gemm1<<<gb, 256, 0, stream>>>(x, W1, dinv, t, N, flags);
    k_agg<true><<<ab, 256, 0, stream>>>(t, csr, cursor, deg, dinv, b1, h, N, E, flags);
    // layer 2
    k_gemm2<<<gb, 256, 0, stream>>>(h, W2, dinv, t, N, flags);
    k_agg<false><<<ab, 256, 0, stream>>>(t, csr, cursor, deg, dinv, b2, h, N, E, flags);
    // pool + head
    k_pool<<<G, 64, 0, stream>>>(h, bat, N, pooled, flags);
    k_out<<<G, 64, 0, stream>>>(pooled, Wout, bout, d_out, G, flags);
}